// Round 1
// 122.091 us; speedup vs baseline: 1.0179x; 1.0179x over previous
//
#include <hip/hip_runtime.h>

#define TRAJ_LEN 25
#define N_SUB 8

typedef float fx4 __attribute__((ext_vector_type(4)));  // native vec for dwordx4 store

// Tsit5 tableau (double precision).
#define CA21 0.161
#define CA31 -0.008480655492356989
#define CA32 0.335480655492357
#define CA41 2.8971530571054935
#define CA42 -6.359448489975075
#define CA43 4.3622954328695815
#define CA51 5.325864828439257
#define CA52 -11.748883564062828
#define CA53 7.4955393428898365
#define CA54 -0.09249506636175525
#define CA61 5.86145544294642
#define CA62 -12.92096931784711
#define CA63 8.159367898576159
#define CA64 -0.071584973281401
#define CA65 -0.028269050394068383
#define CB1 0.09646076681806523
#define CB2 0.01
#define CB3 0.4798896504144996
#define CB4 1.379008574103742
#define CB5 -3.290069515436081
#define CB6 2.324710524099774

struct M2 { double a, b, c, d; };  // [[a, b], [c, d]]

__device__ __forceinline__ M2 mmul(const M2& x, const M2& y) {
    return { x.a * y.a + x.b * y.c, x.a * y.b + x.b * y.d,
             x.c * y.a + x.d * y.c, x.c * y.b + x.d * y.d };
}
__device__ __forceinline__ M2 msc(double s, const M2& x) {
    return { s * x.a, s * x.b, s * x.c, s * x.d };
}
__device__ __forceinline__ M2 madd(const M2& x, const M2& y) {
    return { x.a + y.a, x.b + y.b, x.c + y.c, x.d + y.d };
}
__device__ __forceinline__ M2 eyeph(double h, const M2& x) {  // I + h*X
    return { 1.0 + h * x.a, h * x.b, h * x.c, 1.0 + h * x.d };
}

// Single fused kernel. Wave 0 of each block rebuilds G = S^8 (fp64) and the
// 25 powers into LDS.
//
// Grid is sized so that (2 * grid_threads) % 25 == 0 (blocks = 1000 ->
// S = 256000, 2S/25 = 20480 exact). Consequence: each thread's save-index
// pair (iA, iA+1) is INVARIANT across grid-stride iterations, and the
// second stream (offset S float4 = 2S trajectory points = exactly 20480
// trajectories) shares the same pair. So the g[] table is read ONCE per
// thread into 8 registers, and the inner loop is pure streaming:
// 4 x 8B L2-resident loads, 16 fp32 ops, 2 x dwordx4 stores, 2 ptr adds.
// No per-iteration LDS traffic, no mod-25 branches.
__global__ __launch_bounds__(256) void fused_kernel(
        const float2* __restrict__ x0,
        const float* __restrict__ mat,
        const float* __restrict__ Tp,
        fx4* __restrict__ out, float* __restrict__ out_scalar,
        int n4, int out_last, float nsteps,
        int de) {   // de = (2*grid_threads)/25, with (2*grid_threads)%25 == 0
    __shared__ float4 g[TRAJ_LEN];

    if (threadIdx.x < 64) {  // wave 0 builds the power table
        const double T = (double)Tp[0];
        const double h = (double)(float)(1.0 / ((TRAJ_LEN - 1) * N_SUB));
        const M2 A = { T * (double)mat[0], T * (double)mat[1],
                       T * (double)mat[2], T * (double)mat[3] };

        M2 S1 = A;
        M2 S2 = mmul(A, eyeph(h, msc(CA21, S1)));
        M2 S3 = mmul(A, eyeph(h, madd(msc(CA31, S1), msc(CA32, S2))));
        M2 S4 = mmul(A, eyeph(h, madd(madd(msc(CA41, S1), msc(CA42, S2)), msc(CA43, S3))));
        M2 S5 = mmul(A, eyeph(h, madd(madd(madd(msc(CA51, S1), msc(CA52, S2)), msc(CA53, S3)), msc(CA54, S4))));
        M2 S6 = mmul(A, eyeph(h, madd(madd(madd(madd(msc(CA61, S1), msc(CA62, S2)), msc(CA63, S3)), msc(CA64, S4)), msc(CA65, S5))));
        M2 S = eyeph(h, madd(madd(madd(madd(madd(msc(CB1, S1), msc(CB2, S2)), msc(CB3, S3)), msc(CB4, S4)), msc(CB5, S5)), msc(CB6, S6)));
        M2 G2 = mmul(S, S);
        M2 G4 = mmul(G2, G2);
        M2 G  = mmul(G4, G4);  // S^8 = one save interval

        const int lane = threadIdx.x;
        if (lane < TRAJ_LEN) {
            M2 P = { 1.0, 0.0, 0.0, 1.0 };
            M2 Q = G;
            int n = lane;
            #pragma unroll
            for (int b = 0; b < 5; ++b) {
                if (n & 1) P = mmul(Q, P);
                n >>= 1;
                Q = mmul(Q, Q);
            }
            g[lane] = make_float4((float)P.a, (float)P.b, (float)P.c, (float)P.d);
        }
        if (lane == 0 && blockIdx.x == 0) out_scalar[out_last] = nsteps;
    }
    __syncthreads();

    const int S = gridDim.x * 256;             // grid threads; 2*S % 25 == 0
    const int t0 = blockIdx.x * 256 + threadIdx.x;

    // Fixed save-index pair for this thread (all iterations, both streams).
    const int eA0  = (2 * t0) / TRAJ_LEN;
    const int iA   = 2 * t0 - eA0 * TRAJ_LEN;
    const int wrap = (iA == TRAJ_LEN - 1) ? 1 : 0;  // second point starts next traj
    const int iA1  = wrap ? 0 : iA + 1;

    const float4 g0 = g[iA];    // one-time LDS read, conflict-trivial
    const float4 g1 = g[iA1];

    const int de2 = 2 * de;
    const float2* pA = x0 + eA0;       // stream A trajectory pointer
    const float2* pB = pA + de;        // stream B: +de trajectories, same iA

    int t = t0;
    for (; t + S < n4; t += 2 * S) {
        const float2 a0 = pA[0];
        const float2 a1 = pA[wrap];
        const float2 b0 = pB[0];
        const float2 b1 = pB[wrap];

        fx4 rA, rB;
        rA.x = fmaf(g0.x, a0.x, g0.y * a0.y);
        rA.y = fmaf(g0.z, a0.x, g0.w * a0.y);
        rA.z = fmaf(g1.x, a1.x, g1.y * a1.y);
        rA.w = fmaf(g1.z, a1.x, g1.w * a1.y);
        rB.x = fmaf(g0.x, b0.x, g0.y * b0.y);
        rB.y = fmaf(g0.z, b0.x, g0.w * b0.y);
        rB.z = fmaf(g1.x, b1.x, g1.y * b1.y);
        rB.w = fmaf(g1.z, b1.x, g1.w * b1.y);

        // Plain (cached) stores: the harness's own fill proves full-line
        // streaming stores through TCC hit 6.29 TB/s with zero RFO fetch.
        out[t]     = rA;
        out[t + S] = rB;

        pA += de2;
        pB += de2;
    }
    if (t < n4) {  // tail: at most one float4 (stream A) per thread
        const float2 a0 = pA[0];
        const float2 a1 = pA[wrap];
        fx4 rA;
        rA.x = fmaf(g0.x, a0.x, g0.y * a0.y);
        rA.y = fmaf(g0.z, a0.x, g0.w * a0.y);
        rA.z = fmaf(g1.x, a1.x, g1.y * a1.y);
        rA.w = fmaf(g1.z, a1.x, g1.w * a1.y);
        out[t] = rA;
    }
}

extern "C" void kernel_launch(void* const* d_in, const int* in_sizes, int n_in,
                              void* d_out, int out_size, void* d_ws, size_t ws_size,
                              hipStream_t stream) {
    const float* x0s = (const float*)d_in[0];
    const float* mat = (const float*)d_in[1];
    const float* T   = (const float*)d_in[2];
    float* out = (float*)d_out;

    const int batch = in_sizes[0] / 2;
    const long long nsteps = (long long)batch * (TRAJ_LEN - 1) * N_SUB;

    const int traj_floats = batch * TRAJ_LEN * 2;
    const int n4 = traj_floats / 4;          // 6,553,600 (exact)

    // blocks = 1000 so that 2*stride is an exact multiple of TRAJ_LEN(25):
    // stride = 256000 threads, 2*stride/25 = 20480 -> per-thread save index
    // is loop-invariant and both unrolled streams share it.
    const int blocks = 1000;                 // ~3.9 blocks/CU
    const int stride = blocks * 256;
    const int de = (2 * stride) / TRAJ_LEN;  // 20480, remainder 0 by construction

    hipLaunchKernelGGL(fused_kernel, dim3(blocks), dim3(256), 0, stream,
                       (const float2*)x0s, mat, T,
                       (fx4*)out, out, n4, out_size - 1, (float)nsteps,
                       de);
}

// Round 3
// 121.170 us; speedup vs baseline: 1.0256x; 1.0076x over previous
//
#include <hip/hip_runtime.h>

#define TRAJ_LEN 25
#define N_SUB 8

typedef float fx4 __attribute__((ext_vector_type(4)));  // native vec for dwordx4 store

// Tsit5 tableau (double precision).
#define CA21 0.161
#define CA31 -0.008480655492356989
#define CA32 0.335480655492357
#define CA41 2.8971530571054935
#define CA42 -6.359448489975075
#define CA43 4.3622954328695815
#define CA51 5.325864828439257
#define CA52 -11.748883564062828
#define CA53 7.4955393428898365
#define CA54 -0.09249506636175525
#define CA61 5.86145544294642
#define CA62 -12.92096931784711
#define CA63 8.159367898576159
#define CA64 -0.071584973281401
#define CA65 -0.028269050394068383
#define CB1 0.09646076681806523
#define CB2 0.01
#define CB3 0.4798896504144996
#define CB4 1.379008574103742
#define CB5 -3.290069515436081
#define CB6 2.324710524099774

struct M2 { double a, b, c, d; };  // [[a, b], [c, d]]

__device__ __forceinline__ M2 mmul(const M2& x, const M2& y) {
    return { x.a * y.a + x.b * y.c, x.a * y.b + x.b * y.d,
             x.c * y.a + x.d * y.c, x.c * y.b + x.d * y.d };
}
__device__ __forceinline__ M2 msc(double s, const M2& x) {
    return { s * x.a, s * x.b, s * x.c, s * x.d };
}
__device__ __forceinline__ M2 madd(const M2& x, const M2& y) {
    return { x.a + y.a, x.b + y.b, x.c + y.c, x.d + y.d };
}
__device__ __forceinline__ M2 eyeph(double h, const M2& x) {  // I + h*X
    return { 1.0 + h * x.a, h * x.b, h * x.c, 1.0 + h * x.d };
}

// Single fused kernel. Wave 0 of each block rebuilds G = S^8 (fp64) and the
// 25 powers into LDS.
//
// Grid sized so (2 * grid_threads) % 25 == 0 (blocks = 2000 -> S = 512000,
// 2S/25 = 40960 exact). Each thread's save-index pair (iA, iA+1) is then
// INVARIANT across grid-stride iterations and shared by the second stream,
// so g[] is read once into 8 registers and the loop is pure streaming:
// 4 x 8B L2-resident loads, 16 fp32 ops, 2 x coalesced dwordx4 stores.
//
// blocks = 2000 (31 waves/CU, near-max occupancy) — round-2 discriminator
// (rerun after infra failure): rounds 0/1 timed identically despite very
// different inner loops -> memory-bound; this tests whether 1000 blocks
// was MLP-starved on the store path vs the fill's saturating grid.
__global__ __launch_bounds__(256) void fused_kernel(
        const float2* __restrict__ x0,
        const float* __restrict__ mat,
        const float* __restrict__ Tp,
        fx4* __restrict__ out, float* __restrict__ out_scalar,
        int n4, int out_last, float nsteps,
        int de) {   // de = (2*grid_threads)/25, with (2*grid_threads)%25 == 0
    __shared__ float4 g[TRAJ_LEN];

    if (threadIdx.x < 64) {  // wave 0 builds the power table
        const double T = (double)Tp[0];
        const double h = (double)(float)(1.0 / ((TRAJ_LEN - 1) * N_SUB));
        const M2 A = { T * (double)mat[0], T * (double)mat[1],
                       T * (double)mat[2], T * (double)mat[3] };

        M2 S1 = A;
        M2 S2 = mmul(A, eyeph(h, msc(CA21, S1)));
        M2 S3 = mmul(A, eyeph(h, madd(msc(CA31, S1), msc(CA32, S2))));
        M2 S4 = mmul(A, eyeph(h, madd(madd(msc(CA41, S1), msc(CA42, S2)), msc(CA43, S3))));
        M2 S5 = mmul(A, eyeph(h, madd(madd(madd(msc(CA51, S1), msc(CA52, S2)), msc(CA53, S3)), msc(CA54, S4))));
        M2 S6 = mmul(A, eyeph(h, madd(madd(madd(madd(msc(CA61, S1), msc(CA62, S2)), msc(CA63, S3)), msc(CA64, S4)), msc(CA65, S5))));
        M2 S = eyeph(h, madd(madd(madd(madd(madd(msc(CB1, S1), msc(CB2, S2)), msc(CB3, S3)), msc(CB4, S4)), msc(CB5, S5)), msc(CB6, S6)));
        M2 G2 = mmul(S, S);
        M2 G4 = mmul(G2, G2);
        M2 G  = mmul(G4, G4);  // S^8 = one save interval

        const int lane = threadIdx.x;
        if (lane < TRAJ_LEN) {
            M2 P = { 1.0, 0.0, 0.0, 1.0 };
            M2 Q = G;
            int n = lane;
            #pragma unroll
            for (int b = 0; b < 5; ++b) {
                if (n & 1) P = mmul(Q, P);
                n >>= 1;
                Q = mmul(Q, Q);
            }
            g[lane] = make_float4((float)P.a, (float)P.b, (float)P.c, (float)P.d);
        }
        if (lane == 0 && blockIdx.x == 0) out_scalar[out_last] = nsteps;
    }
    __syncthreads();

    const int S = gridDim.x * 256;             // grid threads; 2*S % 25 == 0
    const int t0 = blockIdx.x * 256 + threadIdx.x;

    // Fixed save-index pair for this thread (all iterations, both streams).
    const int eA0  = (2 * t0) / TRAJ_LEN;
    const int iA   = 2 * t0 - eA0 * TRAJ_LEN;
    const int wrap = (iA == TRAJ_LEN - 1) ? 1 : 0;  // second point starts next traj
    const int iA1  = wrap ? 0 : iA + 1;

    const float4 g0 = g[iA];    // one-time LDS read, conflict-trivial
    const float4 g1 = g[iA1];

    const int de2 = 2 * de;
    const float2* pA = x0 + eA0;       // stream A trajectory pointer
    const float2* pB = pA + de;        // stream B: +de trajectories, same iA

    int t = t0;
    for (; t + S < n4; t += 2 * S) {
        const float2 a0 = pA[0];
        const float2 a1 = pA[wrap];
        const float2 b0 = pB[0];
        const float2 b1 = pB[wrap];

        fx4 rA, rB;
        rA.x = fmaf(g0.x, a0.x, g0.y * a0.y);
        rA.y = fmaf(g0.z, a0.x, g0.w * a0.y);
        rA.z = fmaf(g1.x, a1.x, g1.y * a1.y);
        rA.w = fmaf(g1.z, a1.x, g1.w * a1.y);
        rB.x = fmaf(g0.x, b0.x, g0.y * b0.y);
        rB.y = fmaf(g0.z, b0.x, g0.w * b0.y);
        rB.z = fmaf(g1.x, b1.x, g1.y * b1.y);
        rB.w = fmaf(g1.z, b1.x, g1.w * b1.y);

        out[t]     = rA;
        out[t + S] = rB;

        pA += de2;
        pB += de2;
    }
    if (t < n4) {  // tail: at most one float4 (stream A) per thread
        const float2 a0 = pA[0];
        const float2 a1 = pA[wrap];
        fx4 rA;
        rA.x = fmaf(g0.x, a0.x, g0.y * a0.y);
        rA.y = fmaf(g0.z, a0.x, g0.w * a0.y);
        rA.z = fmaf(g1.x, a1.x, g1.y * a1.y);
        rA.w = fmaf(g1.z, a1.x, g1.w * a1.y);
        out[t] = rA;
    }
}

extern "C" void kernel_launch(void* const* d_in, const int* in_sizes, int n_in,
                              void* d_out, int out_size, void* d_ws, size_t ws_size,
                              hipStream_t stream) {
    const float* x0s = (const float*)d_in[0];
    const float* mat = (const float*)d_in[1];
    const float* T   = (const float*)d_in[2];
    float* out = (float*)d_out;

    const int batch = in_sizes[0] / 2;
    const long long nsteps = (long long)batch * (TRAJ_LEN - 1) * N_SUB;

    const int traj_floats = batch * TRAJ_LEN * 2;
    const int n4 = traj_floats / 4;          // 6,553,600 (exact)

    // blocks must satisfy (2*blocks*256) % 25 == 0 -> blocks % 25 == 0.
    // 2000 blocks = 7.8 blocks/CU = ~31 waves/CU (near-max occupancy).
    const int blocks = 2000;
    const int stride = blocks * 256;
    const int de = (2 * stride) / TRAJ_LEN;  // 40960, remainder 0 by construction

    hipLaunchKernelGGL(fused_kernel, dim3(blocks), dim3(256), 0, stream,
                       (const float2*)x0s, mat, T,
                       (fx4*)out, out, n4, out_size - 1, (float)nsteps,
                       de);
}